// Round 1
// 435.760 us; speedup vs baseline: 1.0309x; 1.0309x over previous
//
#include <hip/hip_runtime.h>
#include <math.h>

// Problem constants (fixed by the reference): B=8, K=512, N=16384, D=128
constexpr int B = 8, K = 512, N = 16384, D = 128;

// ---------------------------------------------------------------------------
// Kernel 1: q[b,n] = sgn(tau_b) * exp( - sum_d src[b,d,n]*conv_w[d] )
//
// Math: argmax_n (logits+g)/tau  ==  argmin_n t*q  with t = -ln(u),
//       q = sgn * exp(-logits). The per-batch bias (tgt_global . w_tgt) is a
//       uniform shift of logits -> softmax/argmax invariant -> DROPPED
//       (tgt_embedding is unused). |tau| is a positive scale -> invariant.
//
// v2 (MLP redesign): previous version had 4 waves/CU each with a 128-long
// sequential load-fma chain -> Little's-law limited to ~0.3 TB/s.
// Now: block = 256 threads = 4 waves; each wave owns 32 of the 128 d's
// (dg = wave id), each lane owns 4 columns (float4). 8 float4 loads are
// batched per step -> >=64 KB in flight per CU (need ~9.2 KB for peak BW).
// Partial d-sums combined through LDS, wave 0 applies exp and stores.
// Grid: B * N/256 = 512 blocks.
// ---------------------------------------------------------------------------
constexpr int TQ = 256;  // columns per block

__global__ __launch_bounds__(256) void k_q(const float* __restrict__ src,
                                           const float* __restrict__ conv_w,
                                           const float* __restrict__ temp,
                                           float* __restrict__ q) {
    const int b  = blockIdx.x / (N / TQ);
    const int nb = blockIdx.x % (N / TQ);
    const int dg = threadIdx.x >> 6;  // wave id 0..3 -> d-group (wave-uniform)
    const int ln = threadIdx.x & 63;
    const float* sp = src + (size_t)b * D * N + (size_t)nb * TQ + ln * 4;
    const int d0 = dg * 32;

    float4 acc = make_float4(0.f, 0.f, 0.f, 0.f);
#pragma unroll
    for (int t = 0; t < 4; ++t) {
        float4 v[8];
#pragma unroll
        for (int j = 0; j < 8; ++j)
            v[j] = *(const float4*)(sp + (size_t)(d0 + t * 8 + j) * N);
#pragma unroll
        for (int j = 0; j < 8; ++j) {
            const float w = conv_w[d0 + t * 8 + j];  // wave-uniform -> s_load
            acc.x = fmaf(v[j].x, w, acc.x);
            acc.y = fmaf(v[j].y, w, acc.y);
            acc.z = fmaf(v[j].z, w, acc.z);
            acc.w = fmaf(v[j].w, w, acc.w);
        }
    }

    __shared__ float4 ps[4][64];
    ps[dg][ln] = acc;
    __syncthreads();
    if (dg == 0) {
        const float4 a0 = ps[0][ln], a1 = ps[1][ln], a2 = ps[2][ln], a3 = ps[3][ln];
        const float sgn = (temp[b] < 0.f) ? -1.f : 1.f;
        float4 o;
        o.x = sgn * expf(-(a0.x + a1.x + a2.x + a3.x));
        o.y = sgn * expf(-(a0.y + a1.y + a2.y + a3.y));
        o.z = sgn * expf(-(a0.z + a1.z + a2.z + a3.z));
        o.w = sgn * expf(-(a0.w + a1.w + a2.w + a3.w));
        ((float4*)(q + (size_t)b * N + (size_t)nb * TQ))[ln] = o;
    }
}

// ---------------------------------------------------------------------------
// Kernel 2: idx[b*K+k] = argmin_n t(u[b,k,n]) * q[b,n]
//   t = -ln(u):  u near 1 (the only possible winners) -> exact series
//                t = w*(1 + w*(1/2 + w/3)), w = 1-u (Sterbenz-exact there);
//                else  t = -log2(u)*ln2 via v_log_f32 (never a contender,
//                P(max u < 0.992) ~ e^-131, so HW log error is harmless).
// First-occurrence tie-break (strict < in scan, lower-index in reductions).
// v2: 4-iteration load batching (8x dwordx4 in flight per lane before the
// compute block) so HBM latency is covered; per-thread visit order over n is
// IDENTICAL to v1 (tid, tid+256, tid+512, ...) -> same tie-break semantics.
// One 256-thread block per (b,k); 4096 blocks. q row (64 KB) stays L2-hot.
// ---------------------------------------------------------------------------
__device__ __forceinline__ float neg_ln(float u) {
    u = fmaxf(u, 1e-10f);                       // clip: (1 - 1e-10) rounds to 1.0f -> upper clip is a no-op
    const float w = 1.0f - u;
    const float tf = __builtin_amdgcn_logf(u) * -0.69314718056f;  // -log2(u)*ln2
    const float tp = w * fmaf(w, fmaf(w, 0.33333334f, 0.5f), 1.0f);
    return (w < 0.0078125f) ? tp : tf;
}

__device__ __forceinline__ void amin_update(float v, int n, float& best, int& bi) {
    if (v < best) { best = v; bi = n; }
}

__global__ __launch_bounds__(256) void k_argmin(const float* __restrict__ gum,
                                                const float* __restrict__ q,
                                                int* __restrict__ idx_out) {
    const int b = blockIdx.x / K;
    const float4* gp = (const float4*)(gum + (size_t)blockIdx.x * N);
    const float4* qp = (const float4*)(q + (size_t)b * N);

    float best = INFINITY;
    int bi = 0;
#pragma unroll
    for (int r4 = 0; r4 < 4; ++r4) {
        const int i0 = threadIdx.x + r4 * 4 * 256;
        float4 g[4], qv[4];
#pragma unroll
        for (int j = 0; j < 4; ++j) {
            g[j]  = gp[i0 + j * 256];
            qv[j] = qp[i0 + j * 256];
        }
#pragma unroll
        for (int j = 0; j < 4; ++j) {
            const int n0 = (i0 + j * 256) * 4;
            amin_update(neg_ln(g[j].x) * qv[j].x, n0 + 0, best, bi);
            amin_update(neg_ln(g[j].y) * qv[j].y, n0 + 1, best, bi);
            amin_update(neg_ln(g[j].z) * qv[j].z, n0 + 2, best, bi);
            amin_update(neg_ln(g[j].w) * qv[j].w, n0 + 3, best, bi);
        }
    }

    // wave reduce (64 lanes), tie -> lower n
    for (int off = 32; off; off >>= 1) {
        float ov = __shfl_down(best, off);
        int oi = __shfl_down(bi, off);
        if (ov < best || (ov == best && oi < bi)) { best = ov; bi = oi; }
    }
    __shared__ float sv[4];
    __shared__ int si[4];
    if ((threadIdx.x & 63) == 0) {
        sv[threadIdx.x >> 6] = best;
        si[threadIdx.x >> 6] = bi;
    }
    __syncthreads();
    if (threadIdx.x == 0) {
#pragma unroll
        for (int j = 1; j < 4; ++j) {
            if (sv[j] < best || (sv[j] == best && si[j] < bi)) { best = sv[j]; bi = si[j]; }
        }
        idx_out[blockIdx.x] = bi;
    }
}

// ---------------------------------------------------------------------------
// Kernel 3: gather
//   out[0 : B*3*K]              = new_points    (b,c,k) = points[b,c,idx]
//   out[B*3*K : B*3*K + B*D*K]  = new_embedding (b,d,k) = src[b,d,idx]
// (scores are exactly one-hot in IEEE: off-argmax (0-y)+y == +0, argmax
//  fl(fl(1-y)+y) == 1 within 1 ulp -- r1 measured absmax 0.0)
// grid (B, 3+D), block K=512; coalesced writes over k.
// ---------------------------------------------------------------------------
__global__ __launch_bounds__(512) void k_gather(const float* __restrict__ points,
                                                const float* __restrict__ src,
                                                const int* __restrict__ idx,
                                                float* __restrict__ out) {
    const int b = blockIdx.x;
    const int row = blockIdx.y;  // 0..2 = points channel, 3.. = embedding dim
    const int k = threadIdx.x;
    const int id = idx[b * K + k];
    if (row < 3) {
        out[((size_t)b * 3 + row) * K + k] = points[((size_t)b * 3 + row) * N + id];
    } else {
        const int d = row - 3;
        out[(size_t)B * 3 * K + ((size_t)b * D + d) * K + k] =
            src[((size_t)b * D + d) * N + id];
    }
}

// ---------------------------------------------------------------------------
extern "C" void kernel_launch(void* const* d_in, const int* in_sizes, int n_in,
                              void* d_out, int out_size, void* d_ws, size_t ws_size,
                              hipStream_t stream) {
    const float* points = (const float*)d_in[0];  // (B,3,N)
    const float* src    = (const float*)d_in[1];  // (B,D,N)
    // d_in[2] = tgt_embedding : provably unused (uniform logit shift)
    const float* temp   = (const float*)d_in[3];  // (B,)
    const float* conv_w = (const float*)d_in[4];  // (2D,) -- only first D used
    const float* gum    = (const float*)d_in[5];  // (B,K,N)
    float* out = (float*)d_out;

    // ws layout (floats): [0, B*N) q | then B*K ints idx
    float* ws = (float*)d_ws;
    float* q = ws;
    int* idxb = (int*)(ws + (size_t)B * N);

    k_q<<<B * (N / TQ), 256, 0, stream>>>(src, conv_w, temp, q);
    k_argmin<<<B * K, 256, 0, stream>>>(gum, q, idxb);
    k_gather<<<dim3(B, 3 + K > 0 ? 3 + D : 3 + D), K, 0, stream>>>(points, src, idxb, out);
}

// Round 2
// 434.745 us; speedup vs baseline: 1.0333x; 1.0023x over previous
//
#include <hip/hip_runtime.h>
#include <math.h>

// Problem constants (fixed by the reference): B=8, K=512, N=16384, D=128
constexpr int B = 8, K = 512, N = 16384, D = 128;

// ---------------------------------------------------------------------------
// Kernel 1: q[b,n] = sgn(tau_b) * exp( - sum_d src[b,d,n]*conv_w[d] )
//
// Math: argmax_n (logits+g)/tau  ==  argmin_n t*q  with t = -ln(u),
//       q = sgn * exp(-logits). The per-batch bias (tgt_global . w_tgt) is a
//       uniform shift of logits -> softmax/argmax invariant -> DROPPED
//       (tgt_embedding is unused). |tau| is a positive scale -> invariant.
//
// block = 256 threads = 4 waves; each wave owns 32 of the 128 d's,
// each lane owns 4 columns (float4). 8 float4 loads batched per step
// -> >=64 KB in flight per CU. Partial d-sums combined via LDS.
// Grid: B * N/256 = 512 blocks.
// ---------------------------------------------------------------------------
constexpr int TQ = 256;  // columns per block

__global__ __launch_bounds__(256) void k_q(const float* __restrict__ src,
                                           const float* __restrict__ conv_w,
                                           const float* __restrict__ temp,
                                           float* __restrict__ q) {
    const int b  = blockIdx.x / (N / TQ);
    const int nb = blockIdx.x % (N / TQ);
    const int dg = threadIdx.x >> 6;  // wave id 0..3 -> d-group (wave-uniform)
    const int ln = threadIdx.x & 63;
    const float* sp = src + (size_t)b * D * N + (size_t)nb * TQ + ln * 4;
    const int d0 = dg * 32;

    float4 acc = make_float4(0.f, 0.f, 0.f, 0.f);
#pragma unroll
    for (int t = 0; t < 4; ++t) {
        float4 v[8];
#pragma unroll
        for (int j = 0; j < 8; ++j)
            v[j] = *(const float4*)(sp + (size_t)(d0 + t * 8 + j) * N);
#pragma unroll
        for (int j = 0; j < 8; ++j) {
            const float w = conv_w[d0 + t * 8 + j];  // wave-uniform -> s_load
            acc.x = fmaf(v[j].x, w, acc.x);
            acc.y = fmaf(v[j].y, w, acc.y);
            acc.z = fmaf(v[j].z, w, acc.z);
            acc.w = fmaf(v[j].w, w, acc.w);
        }
    }

    __shared__ float4 ps[4][64];
    ps[dg][ln] = acc;
    __syncthreads();
    if (dg == 0) {
        const float4 a0 = ps[0][ln], a1 = ps[1][ln], a2 = ps[2][ln], a3 = ps[3][ln];
        const float sgn = (temp[b] < 0.f) ? -1.f : 1.f;
        float4 o;
        o.x = sgn * expf(-(a0.x + a1.x + a2.x + a3.x));
        o.y = sgn * expf(-(a0.y + a1.y + a2.y + a3.y));
        o.z = sgn * expf(-(a0.z + a1.z + a2.z + a3.z));
        o.w = sgn * expf(-(a0.w + a1.w + a2.w + a3.w));
        ((float4*)(q + (size_t)b * N + (size_t)nb * TQ))[ln] = o;
    }
}

// ---------------------------------------------------------------------------
// Kernel 2 (FUSED argmin + gather):
//   idx = argmin_n t(u[b,k,n]) * q[b,n]   with t = -ln(u)
//   then this same block writes the output column k:
//     out[(b*3+c)*K + k]           = points[(b*3+c)*N + idx]   c=0..2
//     out[B*3*K + (b*D+d)*K + k]   = src[(b*D+d)*N + idx]      d=0..127
//
//   t = -ln(u):  u near 1 (the only possible winners) -> exact series
//                t = w*(1 + w*(1/2 + w/3)), w = 1-u (Sterbenz-exact there);
//                else  t = -log2(u)*ln2 via v_log_f32 (never a contender,
//                P(max u < 0.992) ~ e^-131, so HW log error is harmless).
// First-occurrence tie-break (strict < in scan, lower-index in reductions);
// per-thread visit order over n identical to prior rounds -> same semantics.
// (scores are exactly one-hot in IEEE: off-argmax (0-y)+y == +0, argmax
//  fl(fl(1-y)+y) == 1 within 1 ulp -- r1 measured absmax 0.0)
// One 256-thread block per (b,k); 4096 blocks. q row (64 KB) stays L2-hot.
// ---------------------------------------------------------------------------
__device__ __forceinline__ float neg_ln(float u) {
    u = fmaxf(u, 1e-10f);                       // clip: (1 - 1e-10) rounds to 1.0f -> upper clip is a no-op
    const float w = 1.0f - u;
    const float tf = __builtin_amdgcn_logf(u) * -0.69314718056f;  // -log2(u)*ln2
    const float tp = w * fmaf(w, fmaf(w, 0.33333334f, 0.5f), 1.0f);
    return (w < 0.0078125f) ? tp : tf;
}

__device__ __forceinline__ void amin_update(float v, int n, float& best, int& bi) {
    if (v < best) { best = v; bi = n; }
}

__global__ __launch_bounds__(256) void k_argmin_gather(
    const float* __restrict__ gum, const float* __restrict__ q,
    const float* __restrict__ points, const float* __restrict__ src,
    float* __restrict__ out) {
    const int b = blockIdx.x / K;
    const int k = blockIdx.x % K;
    const float4* gp = (const float4*)(gum + (size_t)blockIdx.x * N);
    const float4* qp = (const float4*)(q + (size_t)b * N);

    float best = INFINITY;
    int bi = 0;
#pragma unroll
    for (int r4 = 0; r4 < 4; ++r4) {
        const int i0 = threadIdx.x + r4 * 4 * 256;
        float4 g[4], qv[4];
#pragma unroll
        for (int j = 0; j < 4; ++j) {
            g[j]  = gp[i0 + j * 256];
            qv[j] = qp[i0 + j * 256];
        }
#pragma unroll
        for (int j = 0; j < 4; ++j) {
            const int n0 = (i0 + j * 256) * 4;
            amin_update(neg_ln(g[j].x) * qv[j].x, n0 + 0, best, bi);
            amin_update(neg_ln(g[j].y) * qv[j].y, n0 + 1, best, bi);
            amin_update(neg_ln(g[j].z) * qv[j].z, n0 + 2, best, bi);
            amin_update(neg_ln(g[j].w) * qv[j].w, n0 + 3, best, bi);
        }
    }

    // wave reduce (64 lanes), tie -> lower n
    for (int off = 32; off; off >>= 1) {
        float ov = __shfl_down(best, off);
        int oi = __shfl_down(bi, off);
        if (ov < best || (ov == best && oi < bi)) { best = ov; bi = oi; }
    }
    __shared__ float sv[4];
    __shared__ int si[4];
    __shared__ int sidx;
    if ((threadIdx.x & 63) == 0) {
        sv[threadIdx.x >> 6] = best;
        si[threadIdx.x >> 6] = bi;
    }
    __syncthreads();
    if (threadIdx.x == 0) {
#pragma unroll
        for (int j = 1; j < 4; ++j) {
            if (sv[j] < best || (sv[j] == best && si[j] < bi)) { best = sv[j]; bi = si[j]; }
        }
        sidx = bi;
    }
    __syncthreads();

    // ---- fused gather: threads 0..130 write output column k ----
    const int row = threadIdx.x;  // 0..2 = points channel, 3.. = embedding dim
    if (row < 3 + D) {
        const int id = sidx;
        if (row < 3) {
            out[((size_t)b * 3 + row) * K + k] = points[((size_t)b * 3 + row) * N + id];
        } else {
            const int d = row - 3;
            out[(size_t)B * 3 * K + ((size_t)b * D + d) * K + k] =
                src[((size_t)b * D + d) * N + id];
        }
    }
}

// ---------------------------------------------------------------------------
extern "C" void kernel_launch(void* const* d_in, const int* in_sizes, int n_in,
                              void* d_out, int out_size, void* d_ws, size_t ws_size,
                              hipStream_t stream) {
    const float* points = (const float*)d_in[0];  // (B,3,N)
    const float* src    = (const float*)d_in[1];  // (B,D,N)
    // d_in[2] = tgt_embedding : provably unused (uniform logit shift)
    const float* temp   = (const float*)d_in[3];  // (B,)
    const float* conv_w = (const float*)d_in[4];  // (2D,) -- only first D used
    const float* gum    = (const float*)d_in[5];  // (B,K,N)
    float* out = (float*)d_out;

    // ws layout (floats): [0, B*N) q
    float* q = (float*)d_ws;

    k_q<<<B * (N / TQ), 256, 0, stream>>>(src, conv_w, temp, q);
    k_argmin_gather<<<B * K, 256, 0, stream>>>(gum, q, points, src, out);
}